// Round 19
// baseline (34.094 us; speedup 1.0000x reference)
//
#include <hip/hip_runtime.h>

typedef float f32x4 __attribute__((ext_vector_type(4)));
typedef int   i32x4 __attribute__((ext_vector_type(4)));

#define KC 512
#define DC 64
#define HWs 4096
#define NPTS 131072
#define NGRP 4096              // 32 points per wave
#define NBLK 512               // 8 waves/block, 256 pts/block
#define SE 512.0f              // codebook scale (e' = 512 e)
#define SZ 64.0f               // z scale (z' = 64 z)
#define CBASE 4096.0f          // keeps packed scores positive

template <bool HI>
static __device__ inline int pk8(float a, float b, int old) {
    return __builtin_amdgcn_cvt_pk_fp8_f32(a, b, old, HI);
}
static __device__ inline long mk64(int lo, int hi) {
    return (long)(((unsigned long)(unsigned)hi << 32) | (unsigned)lo);
}
static __device__ inline int pack4(float a, float b, float c, float d) {
    int w = pk8<false>(a, b, 0);
    return pk8<true>(c, d, w);
}

// --- prep: fp32 codebook -> fp8 image (x512, tile order) + ini bytes --------
// Entry j (byte j*16) holds dims [8c..8c+7],[32+8c..+7] of code r, where
// r = ((j>>6)<<4)|(j&15), c = (j>>4)&3.  Search lane (g,pl) at tile t reads
// img[t*64 + g*16 + pl] -> consecutive lanes read consecutive 16B: coalesced,
// and the whole image is 32 KB = L1-resident.   [verified in R10]
__global__ __launch_bounds__(256) void vq_prep(const float* __restrict__ cbf,
                                               i32x4* __restrict__ img,
                                               unsigned char* __restrict__ iniG) {
    const int j = blockIdx.x * 256 + threadIdx.x;   // 0..2047
    const int r = ((j >> 6) << 4) | (j & 15);
    const int c = (j >> 4) & 3;
    const float* src = cbf + (size_t)r * DC + 8 * c;
    f32x4 a0 = *(const f32x4*)(src);
    f32x4 a1 = *(const f32x4*)(src + 4);
    f32x4 b0 = *(const f32x4*)(src + 32);
    f32x4 b1 = *(const f32x4*)(src + 36);
    a0 *= SE; a1 *= SE; b0 *= SE; b1 *= SE;
    i32x4 w = {pack4(a0[0], a0[1], a0[2], a0[3]),
               pack4(a1[0], a1[1], a1[2], a1[3]),
               pack4(b0[0], b0[1], b0[2], b0[3]),
               pack4(b1[0], b1[1], b1[2], b1[3])};
    img[j] = w;
    float ss = 0.f;
#pragma unroll
    for (int k = 0; k < 4; ++k) {
        ss = fmaf(a0[k], a0[k], ss); ss = fmaf(a1[k], a1[k], ss);
        ss = fmaf(b0[k], b0[k], ss); ss = fmaf(b1[k], b1[k], ss);
    }
    // within a 64-lane group r-high (j>>6) is constant; lane = c*16 + pl
    ss += __shfl_xor(ss, 16, 64);
    ss += __shfl_xor(ss, 32, 64);
    if (c == 0) {
        int w8 = pk8<false>(-0.0625f * ss, 0.f, 0);   // -0.5*SZ*SE*||e||^2 scaled
        iniG[(r & 15) * 32 + (r >> 4)] = (unsigned char)(w8 & 0xff);
    }
}

// --- main: zero-LDS MFMA search (codebook image L1-resident) ----------------
// score = CBASE - 0.5*SZ*SE*||e||^2 + z'.e'  (argmax == argmin distance)
// norm folded into ini-MFMA (A byte0 on g==0 = fp8(-||e'||^2/16), B byte0=1.0).
// No staging, no barrier, no LDS: per-wave phases are load-z -> loop -> store.
__global__ __launch_bounds__(512) void vq_search(const float* __restrict__ z,
                                                 const float* __restrict__ cbf,
                                                 const i32x4* __restrict__ img,
                                                 const unsigned int* __restrict__ iniG,
                                                 float* __restrict__ outq,
                                                 float* __restrict__ partial) {
    const int tid = threadIdx.x;
    const int lane = tid & 63, wid = tid >> 6;
    const int g = lane >> 4, pl = lane & 15;

    const int wg = blockIdx.x * 8 + wid;         // 0..4095
    const int p0 = wg * 32;
    const int b  = p0 >> 12;                     // 32 | 4096 -> same b per wave
    const int s0 = (p0 & (HWs - 1)) + pl;
    const float* zbase = z + (size_t)b * (DC * HWs) + s0;

    // ---- z: 2 points (pl, pl+16) x 16 dims; fp32 kept + fp8 B-frags -------
    float zt[32];
#pragma unroll
    for (int j = 0; j < 8; ++j) {
        zt[j]      = zbase[(size_t)(8 * g + j) * HWs];
        zt[8 + j]  = zbase[(size_t)(32 + 8 * g + j) * HWs];
        zt[16 + j] = zbase[(size_t)(8 * g + j) * HWs + 16];
        zt[24 + j] = zbase[(size_t)(32 + 8 * g + j) * HWs + 16];
    }
    const long zA0 = mk64(pack4(SZ * zt[0],  SZ * zt[1],  SZ * zt[2],  SZ * zt[3]),
                          pack4(SZ * zt[4],  SZ * zt[5],  SZ * zt[6],  SZ * zt[7]));
    const long zA1 = mk64(pack4(SZ * zt[8],  SZ * zt[9],  SZ * zt[10], SZ * zt[11]),
                          pack4(SZ * zt[12], SZ * zt[13], SZ * zt[14], SZ * zt[15]));
    const long zB0 = mk64(pack4(SZ * zt[16], SZ * zt[17], SZ * zt[18], SZ * zt[19]),
                          pack4(SZ * zt[20], SZ * zt[21], SZ * zt[22], SZ * zt[23]));
    const long zB1 = mk64(pack4(SZ * zt[24], SZ * zt[25], SZ * zt[26], SZ * zt[27]),
                          pack4(SZ * zt[28], SZ * zt[29], SZ * zt[30], SZ * zt[31]));

    // per-lane ini bytes for codes 16t+pl, t=0..31 (L1-hot 32B reads)
    const i32x4 iw0 = *(const i32x4*)((const char*)iniG + pl * 32);
    const i32x4 iw1 = *(const i32x4*)((const char*)iniG + pl * 32 + 16);
    const unsigned gmask = (g == 0) ? 0xffu : 0u;
    const long bunit = (g == 0) ? 0x38L : 0L;    // fp8 1.0 at k=0
    const f32x4 cb4 = {CBASE, CBASE, CBASE, CBASE};

    unsigned best0 = 0u, best1 = 0u;
#pragma unroll
    for (int t = 0; t < 32; ++t) {
        const unsigned wrd = (t < 16) ? (unsigned)iw0[(t >> 2) & 3]
                                      : (unsigned)iw1[((t - 16) >> 2) & 3];
        const long a_ini = (long)((wrd >> ((t & 3) * 8)) & gmask);
        i32x4 aw = img[t * 64 + lane];           // coalesced 1KB/wave, L1-resident
        long A0 = mk64(aw[0], aw[1]);            // dims 8g..8g+7
        long A1 = mk64(aw[2], aw[3]);            // dims 32+8g..32+8g+7
        f32x4 ia = __builtin_amdgcn_mfma_f32_16x16x32_fp8_fp8(a_ini, bunit, cb4, 0, 0, 0);
        f32x4 acc0 = __builtin_amdgcn_mfma_f32_16x16x32_fp8_fp8(A0, zA0, ia, 0, 0, 0);
        acc0 = __builtin_amdgcn_mfma_f32_16x16x32_fp8_fp8(A1, zA1, acc0, 0, 0, 0);
        f32x4 acc1 = __builtin_amdgcn_mfma_f32_16x16x32_fp8_fp8(A0, zB0, ia, 0, 0, 0);
        acc1 = __builtin_amdgcn_mfma_f32_16x16x32_fp8_fp8(A1, zB1, acc1, 0, 0, 0);
#pragma unroll
        for (int j = 0; j < 4; ++j) {
            const unsigned code = (unsigned)(16 * t + 4 * g + j);
            unsigned u0 = __builtin_bit_cast(unsigned, acc0[j]) | code;
            unsigned u1 = __builtin_bit_cast(unsigned, acc1[j]) | code;
            best0 = best0 > u0 ? best0 : u0;
            best1 = best1 > u1 ? best1 : u1;
        }
    }

    // argmax across the 4 g-groups holding the same point
#pragma unroll
    for (int m = 16; m <= 32; m <<= 1) {
        unsigned o0 = (unsigned)__shfl_xor((int)best0, m, 64);
        unsigned o1 = (unsigned)__shfl_xor((int)best1, m, 64);
        best0 = best0 > o0 ? best0 : o0;
        best1 = best1 > o1 ? best1 : o1;
    }
    const int bidx0 = best0 & 511, bidx1 = best1 & 511;

    // epilogue: gather exact fp32 code rows (L2-hot), write out, loss
    float err = 0.f;
    float* obase = outq + (size_t)b * (DC * HWs) + s0;
    {
        const float* qp = cbf + (size_t)bidx0 * DC + 8 * g;
        f32x4 q0 = *(const f32x4*)(qp);
        f32x4 q1 = *(const f32x4*)(qp + 4);
        f32x4 q2 = *(const f32x4*)(qp + 32);
        f32x4 q3 = *(const f32x4*)(qp + 36);
#pragma unroll
        for (int j = 0; j < 4; ++j) {
            size_t o0_ = (size_t)(8 * g + j) * HWs;
            size_t o1_ = (size_t)(8 * g + 4 + j) * HWs;
            size_t o2_ = (size_t)(32 + 8 * g + j) * HWs;
            size_t o3_ = (size_t)(32 + 8 * g + 4 + j) * HWs;
            obase[o0_] = q0[j]; float d0 = q0[j] - zt[j];      err = fmaf(d0, d0, err);
            obase[o1_] = q1[j]; float d1 = q1[j] - zt[4 + j];  err = fmaf(d1, d1, err);
            obase[o2_] = q2[j]; float d2 = q2[j] - zt[8 + j];  err = fmaf(d2, d2, err);
            obase[o3_] = q3[j]; float d3 = q3[j] - zt[12 + j]; err = fmaf(d3, d3, err);
        }
    }
    {
        const float* qp = cbf + (size_t)bidx1 * DC + 8 * g;
        f32x4 q0 = *(const f32x4*)(qp);
        f32x4 q1 = *(const f32x4*)(qp + 4);
        f32x4 q2 = *(const f32x4*)(qp + 32);
        f32x4 q3 = *(const f32x4*)(qp + 36);
#pragma unroll
        for (int j = 0; j < 4; ++j) {
            size_t o0_ = (size_t)(8 * g + j) * HWs + 16;
            size_t o1_ = (size_t)(8 * g + 4 + j) * HWs + 16;
            size_t o2_ = (size_t)(32 + 8 * g + j) * HWs + 16;
            size_t o3_ = (size_t)(32 + 8 * g + 4 + j) * HWs + 16;
            obase[o0_] = q0[j]; float d0 = q0[j] - zt[16 + j]; err = fmaf(d0, d0, err);
            obase[o1_] = q1[j]; float d1 = q1[j] - zt[20 + j]; err = fmaf(d1, d1, err);
            obase[o2_] = q2[j]; float d2 = q2[j] - zt[24 + j]; err = fmaf(d2, d2, err);
            obase[o3_] = q3[j]; float d3 = q3[j] - zt[28 + j]; err = fmaf(d3, d3, err);
        }
    }

    // wave reduce -> per-wave partial
#pragma unroll
    for (int off = 32; off; off >>= 1) err += __shfl_down(err, off, 64);
    if (lane == 0) partial[wg] = err;
}

// --- final loss reduction ---------------------------------------------------
__global__ __launch_bounds__(256) void vq_loss(const float* __restrict__ partial,
                                               float* __restrict__ loss_out) {
    float s = 0.f;
#pragma unroll
    for (int q = 0; q < NGRP / 256; ++q) s += partial[q * 256 + threadIdx.x];
#pragma unroll
    for (int off = 32; off; off >>= 1) s += __shfl_down(s, off, 64);
    __shared__ float red[4];
    if ((threadIdx.x & 63) == 0) red[threadIdx.x >> 6] = s;
    __syncthreads();
    if (threadIdx.x == 0)
        loss_out[0] = 1.25f * ((red[0] + red[1]) + (red[2] + red[3])) / 8388608.0f;
}

extern "C" void kernel_launch(void* const* d_in, const int* in_sizes, int n_in,
                              void* d_out, int out_size, void* d_ws, size_t ws_size,
                              hipStream_t stream) {
    const float* z   = (const float*)d_in[0];    // [32,64,64,64] f32
    const float* cbf = (const float*)d_in[1];    // [512,64] f32
    float* outq = (float*)d_out;                 // 8388608 + 1 (loss)
    float* loss = outq + 8388608;

    i32x4* img = (i32x4*)d_ws;                                 // 32 KB fp8 image
    unsigned char* iniG = (unsigned char*)d_ws + 32768;        // 512 B ini
    float* partial = (float*)((char*)d_ws + 32768 + 512);      // 16 KB partials

    vq_prep<<<8, 256, 0, stream>>>(cbf, img, iniG);
    vq_search<<<NBLK, 512, 0, stream>>>(z, cbf, img, (const unsigned int*)iniG,
                                        outq, partial);
    vq_loss<<<1, 256, 0, stream>>>(partial, loss);
}

// Round 20
// 23.616 us; speedup vs baseline: 1.4437x; 1.4437x over previous
//
#include <hip/hip_runtime.h>

typedef float f32x4 __attribute__((ext_vector_type(4)));
typedef int   i32x4 __attribute__((ext_vector_type(4)));

#define KC 512
#define DC 64
#define HWs 4096
#define NPTS 131072
#define NGRP 4096              // 32 points per wave
#define NBLK 256               // 16 waves/block, 512 pts/block, 1 block/CU
#define SE 512.0f              // codebook scale (e' = 512 e)
#define SZ 64.0f               // z scale (z' = 64 z)
#define CBASE 4096.0f          // keeps packed scores positive

template <bool HI>
static __device__ inline int pk8(float a, float b, int old) {
    return __builtin_amdgcn_cvt_pk_fp8_f32(a, b, old, HI);
}
static __device__ inline long mk64(int lo, int hi) {
    return (long)(((unsigned long)(unsigned)hi << 32) | (unsigned)lo);
}
static __device__ inline int pack4(float a, float b, float c, float d) {
    int w = pk8<false>(a, b, 0);
    return pk8<true>(c, d, w);
}

// --- fused: staging + MFMA search (R15 champion, 1 block/CU variant) --------
// One 1024-thread block per CU: the 128 KB codebook L2 read + pack staging is
// paid once per CU instead of twice (R15's only remaining per-block fixed
// cost).  Occupancy identical (16 waves/CU = 4/SIMD).  Everything else is
// byte-identical R15: score = CBASE - 0.5*SZ*SE*||e||^2 + z'.e' (argmax ==
// argmin distance), norm folded into ini-MFMA, LDS image entry
// j = t*64 + g*16 + pl at byte j*16 -> loop read lane*16+t*1024 is linear in
// lane (conflict-free), zt kept in registers for the loss.
__global__ __launch_bounds__(1024, 4) void vq_search(const float* __restrict__ z,
                                                     const float* __restrict__ cbf,
                                                     float* __restrict__ outq,
                                                     float* __restrict__ partial) {
    __shared__ unsigned int cbL[KC * 16];   // 32 KB fp8 image (tile order)
    __shared__ unsigned int iniT[128];      // 512 ini bytes, [pl][t]
    const int tid = threadIdx.x;
    const int lane = tid & 63, wid = tid >> 6;   // 16 waves
    const int g = lane >> 4, pl = lane & 15;

    // ---- stage: fp32 codebook (coalesced) -> fp8 LDS image + ini bytes ----
    for (int pass = 0; pass < 2; ++pass) {
        const int i = pass * 1024 + tid;              // 4 consecutive thr = 1 row
        const int r = i >> 2, c = i & 3;
        const float* src = cbf + (size_t)r * DC + 8 * c;
        f32x4 a0 = *(const f32x4*)(src);
        f32x4 a1 = *(const f32x4*)(src + 4);
        f32x4 b0 = *(const f32x4*)(src + 32);
        f32x4 b1 = *(const f32x4*)(src + 36);
        a0 *= SE; a1 *= SE; b0 *= SE; b1 *= SE;
        i32x4 w = {pack4(a0[0], a0[1], a0[2], a0[3]),     // dims 8c..8c+3
                   pack4(a1[0], a1[1], a1[2], a1[3]),     // dims 8c+4..8c+7
                   pack4(b0[0], b0[1], b0[2], b0[3]),     // dims 32+8c..+3
                   pack4(b1[0], b1[1], b1[2], b1[3])};    // dims 32+8c+4..+7
        // entry j = (r>>4)*64 + c*16 + (r&15); byte j*16
        *(i32x4*)((char*)cbL + (size_t)(r >> 4) * 1024 + c * 256 + (r & 15) * 16) = w;
        float ss = 0.f;
#pragma unroll
        for (int k = 0; k < 4; ++k) {
            ss = fmaf(a0[k], a0[k], ss); ss = fmaf(a1[k], a1[k], ss);
            ss = fmaf(b0[k], b0[k], ss); ss = fmaf(b1[k], b1[k], ss);
        }
        ss += __shfl_xor(ss, 1, 64);                  // sum the 4 chunks
        ss += __shfl_xor(ss, 2, 64);                  // (4 lanes share a row)
        if (c == 0) {
            int w8 = pk8<false>(-0.0625f * ss, 0.f, 0);
            ((unsigned char*)iniT)[(r & 15) * 32 + (r >> 4)] = (unsigned char)(w8 & 0xff);
        }
    }
    __syncthreads();

    const int wg = blockIdx.x * 16 + wid;        // 0..4095
    const int p0 = wg * 32;
    const int b  = p0 >> 12;                     // 32 | 4096 -> same b per wave
    const int s0 = (p0 & (HWs - 1)) + pl;
    const float* zbase = z + (size_t)b * (DC * HWs) + s0;

    // ---- z: 2 points (pl, pl+16) x 16 dims; fp32 kept + fp8 B-frags -------
    float zt[32];
#pragma unroll
    for (int j = 0; j < 8; ++j) {
        zt[j]      = zbase[(size_t)(8 * g + j) * HWs];
        zt[8 + j]  = zbase[(size_t)(32 + 8 * g + j) * HWs];
        zt[16 + j] = zbase[(size_t)(8 * g + j) * HWs + 16];
        zt[24 + j] = zbase[(size_t)(32 + 8 * g + j) * HWs + 16];
    }
    const long zA0 = mk64(pack4(SZ * zt[0],  SZ * zt[1],  SZ * zt[2],  SZ * zt[3]),
                          pack4(SZ * zt[4],  SZ * zt[5],  SZ * zt[6],  SZ * zt[7]));
    const long zA1 = mk64(pack4(SZ * zt[8],  SZ * zt[9],  SZ * zt[10], SZ * zt[11]),
                          pack4(SZ * zt[12], SZ * zt[13], SZ * zt[14], SZ * zt[15]));
    const long zB0 = mk64(pack4(SZ * zt[16], SZ * zt[17], SZ * zt[18], SZ * zt[19]),
                          pack4(SZ * zt[20], SZ * zt[21], SZ * zt[22], SZ * zt[23]));
    const long zB1 = mk64(pack4(SZ * zt[24], SZ * zt[25], SZ * zt[26], SZ * zt[27]),
                          pack4(SZ * zt[28], SZ * zt[29], SZ * zt[30], SZ * zt[31]));

    // per-lane ini bytes for codes 16t+pl, t=0..31
    const i32x4 iw0 = *(const i32x4*)((const char*)iniT + pl * 32);
    const i32x4 iw1 = *(const i32x4*)((const char*)iniT + pl * 32 + 16);
    const unsigned gmask = (g == 0) ? 0xffu : 0u;
    const long bunit = (g == 0) ? 0x38L : 0L;    // fp8 1.0 at k=0
    const f32x4 cb4 = {CBASE, CBASE, CBASE, CBASE};
    const char* cbbase = (const char*)cbL + lane * 16;   // linear in lane

    unsigned best0 = 0u, best1 = 0u;
#pragma unroll
    for (int t = 0; t < 32; ++t) {
        const unsigned wrd = (t < 16) ? (unsigned)iw0[(t >> 2) & 3]
                                      : (unsigned)iw1[((t - 16) >> 2) & 3];
        const long a_ini = (long)((wrd >> ((t & 3) * 8)) & gmask);
        i32x4 aw = *(const i32x4*)(cbbase + (size_t)t * 1024);   // conflict-free
        long A0 = mk64(aw[0], aw[1]);            // dims 8g..8g+7
        long A1 = mk64(aw[2], aw[3]);            // dims 32+8g..32+8g+7
        f32x4 ia = __builtin_amdgcn_mfma_f32_16x16x32_fp8_fp8(a_ini, bunit, cb4, 0, 0, 0);
        f32x4 acc0 = __builtin_amdgcn_mfma_f32_16x16x32_fp8_fp8(A0, zA0, ia, 0, 0, 0);
        acc0 = __builtin_amdgcn_mfma_f32_16x16x32_fp8_fp8(A1, zA1, acc0, 0, 0, 0);
        f32x4 acc1 = __builtin_amdgcn_mfma_f32_16x16x32_fp8_fp8(A0, zB0, ia, 0, 0, 0);
        acc1 = __builtin_amdgcn_mfma_f32_16x16x32_fp8_fp8(A1, zB1, acc1, 0, 0, 0);
#pragma unroll
        for (int j = 0; j < 4; ++j) {
            const unsigned code = (unsigned)(16 * t + 4 * g + j);
            unsigned u0 = __builtin_bit_cast(unsigned, acc0[j]) | code;
            unsigned u1 = __builtin_bit_cast(unsigned, acc1[j]) | code;
            best0 = best0 > u0 ? best0 : u0;
            best1 = best1 > u1 ? best1 : u1;
        }
    }

    // argmax across the 4 g-groups holding the same point
#pragma unroll
    for (int m = 16; m <= 32; m <<= 1) {
        unsigned o0 = (unsigned)__shfl_xor((int)best0, m, 64);
        unsigned o1 = (unsigned)__shfl_xor((int)best1, m, 64);
        best0 = best0 > o0 ? best0 : o0;
        best1 = best1 > o1 ? best1 : o1;
    }
    const int bidx0 = best0 & 511, bidx1 = best1 & 511;

    // epilogue: gather exact fp32 code rows (L2-hot), write out, loss
    float err = 0.f;
    float* obase = outq + (size_t)b * (DC * HWs) + s0;
    {
        const float* qp = cbf + (size_t)bidx0 * DC + 8 * g;
        f32x4 q0 = *(const f32x4*)(qp);
        f32x4 q1 = *(const f32x4*)(qp + 4);
        f32x4 q2 = *(const f32x4*)(qp + 32);
        f32x4 q3 = *(const f32x4*)(qp + 36);
#pragma unroll
        for (int j = 0; j < 4; ++j) {
            size_t o0_ = (size_t)(8 * g + j) * HWs;
            size_t o1_ = (size_t)(8 * g + 4 + j) * HWs;
            size_t o2_ = (size_t)(32 + 8 * g + j) * HWs;
            size_t o3_ = (size_t)(32 + 8 * g + 4 + j) * HWs;
            obase[o0_] = q0[j]; float d0 = q0[j] - zt[j];      err = fmaf(d0, d0, err);
            obase[o1_] = q1[j]; float d1 = q1[j] - zt[4 + j];  err = fmaf(d1, d1, err);
            obase[o2_] = q2[j]; float d2 = q2[j] - zt[8 + j];  err = fmaf(d2, d2, err);
            obase[o3_] = q3[j]; float d3 = q3[j] - zt[12 + j]; err = fmaf(d3, d3, err);
        }
    }
    {
        const float* qp = cbf + (size_t)bidx1 * DC + 8 * g;
        f32x4 q0 = *(const f32x4*)(qp);
        f32x4 q1 = *(const f32x4*)(qp + 4);
        f32x4 q2 = *(const f32x4*)(qp + 32);
        f32x4 q3 = *(const f32x4*)(qp + 36);
#pragma unroll
        for (int j = 0; j < 4; ++j) {
            size_t o0_ = (size_t)(8 * g + j) * HWs + 16;
            size_t o1_ = (size_t)(8 * g + 4 + j) * HWs + 16;
            size_t o2_ = (size_t)(32 + 8 * g + j) * HWs + 16;
            size_t o3_ = (size_t)(32 + 8 * g + 4 + j) * HWs + 16;
            obase[o0_] = q0[j]; float d0 = q0[j] - zt[16 + j]; err = fmaf(d0, d0, err);
            obase[o1_] = q1[j]; float d1 = q1[j] - zt[20 + j]; err = fmaf(d1, d1, err);
            obase[o2_] = q2[j]; float d2 = q2[j] - zt[24 + j]; err = fmaf(d2, d2, err);
            obase[o3_] = q3[j]; float d3 = q3[j] - zt[28 + j]; err = fmaf(d3, d3, err);
        }
    }

    // wave reduce -> per-wave partial
#pragma unroll
    for (int off = 32; off; off >>= 1) err += __shfl_down(err, off, 64);
    if (lane == 0) partial[wg] = err;
}

// --- final loss reduction ---------------------------------------------------
__global__ __launch_bounds__(256) void vq_loss(const float* __restrict__ partial,
                                               float* __restrict__ loss_out) {
    float s = 0.f;
#pragma unroll
    for (int q = 0; q < NGRP / 256; ++q) s += partial[q * 256 + threadIdx.x];
#pragma unroll
    for (int off = 32; off; off >>= 1) s += __shfl_down(s, off, 64);
    __shared__ float red[4];
    if ((threadIdx.x & 63) == 0) red[threadIdx.x >> 6] = s;
    __syncthreads();
    if (threadIdx.x == 0)
        loss_out[0] = 1.25f * ((red[0] + red[1]) + (red[2] + red[3])) / 8388608.0f;
}

extern "C" void kernel_launch(void* const* d_in, const int* in_sizes, int n_in,
                              void* d_out, int out_size, void* d_ws, size_t ws_size,
                              hipStream_t stream) {
    const float* z   = (const float*)d_in[0];    // [32,64,64,64] f32
    const float* cbf = (const float*)d_in[1];    // [512,64] f32
    float* outq = (float*)d_out;                 // 8388608 + 1 (loss)
    float* loss = outq + 8388608;
    float* partial = (float*)d_ws;               // 4096 f32

    vq_search<<<NBLK, 1024, 0, stream>>>(z, cbf, outq, partial);
    vq_loss<<<1, 256, 0, stream>>>(partial, loss);
}

// Round 21
// 21.013 us; speedup vs baseline: 1.6225x; 1.1238x over previous
//
#include <hip/hip_runtime.h>

typedef float f32x4 __attribute__((ext_vector_type(4)));
typedef int   i32x4 __attribute__((ext_vector_type(4)));

#define KC 512
#define DC 64
#define HWs 4096
#define NPTS 131072
#define NGRP 4096              // 32 points per wave
#define NBLK 256               // 16 waves/block, 512 pts/block, 1 block/CU
#define SE 512.0f              // codebook scale (e' = 512 e)
#define SZ 64.0f               // z scale (z' = 64 z)
#define CBASE 4096.0f          // keeps packed scores positive

template <bool HI>
static __device__ inline int pk8(float a, float b, int old) {
    return __builtin_amdgcn_cvt_pk_fp8_f32(a, b, old, HI);
}
static __device__ inline long mk64(int lo, int hi) {
    return (long)(((unsigned long)(unsigned)hi << 32) | (unsigned)lo);
}
static __device__ inline int pack4(float a, float b, float c, float d) {
    int w = pk8<false>(a, b, 0);
    return pk8<true>(c, d, w);
}

// --- fused: staging + MFMA search (R20 champion + non-temporal stores) ------
// One 1024-thread block per CU (staging paid once/CU).  Output stores are
// write-once/never-reread -> nontemporal, so they don't evict the L2-hot
// codebook rows (epilogue gather) or the L3/L2-served z lines.
// score = CBASE - 0.5*SZ*SE*||e||^2 + z'.e'  (argmax == argmin distance);
// norm folded into ini-MFMA; LDS image entry j = t*64+g*16+pl at byte j*16 ->
// loop read lane*16+t*1024 linear in lane (conflict-free); zt kept in regs.
__global__ __launch_bounds__(1024, 4) void vq_search(const float* __restrict__ z,
                                                     const float* __restrict__ cbf,
                                                     float* __restrict__ outq,
                                                     float* __restrict__ partial) {
    __shared__ unsigned int cbL[KC * 16];   // 32 KB fp8 image (tile order)
    __shared__ unsigned int iniT[128];      // 512 ini bytes, [pl][t]
    const int tid = threadIdx.x;
    const int lane = tid & 63, wid = tid >> 6;   // 16 waves
    const int g = lane >> 4, pl = lane & 15;

    // ---- stage: fp32 codebook (coalesced) -> fp8 LDS image + ini bytes ----
    for (int pass = 0; pass < 2; ++pass) {
        const int i = pass * 1024 + tid;              // 4 consecutive thr = 1 row
        const int r = i >> 2, c = i & 3;
        const float* src = cbf + (size_t)r * DC + 8 * c;
        f32x4 a0 = *(const f32x4*)(src);
        f32x4 a1 = *(const f32x4*)(src + 4);
        f32x4 b0 = *(const f32x4*)(src + 32);
        f32x4 b1 = *(const f32x4*)(src + 36);
        a0 *= SE; a1 *= SE; b0 *= SE; b1 *= SE;
        i32x4 w = {pack4(a0[0], a0[1], a0[2], a0[3]),     // dims 8c..8c+3
                   pack4(a1[0], a1[1], a1[2], a1[3]),     // dims 8c+4..8c+7
                   pack4(b0[0], b0[1], b0[2], b0[3]),     // dims 32+8c..+3
                   pack4(b1[0], b1[1], b1[2], b1[3])};    // dims 32+8c+4..+7
        // entry j = (r>>4)*64 + c*16 + (r&15); byte j*16
        *(i32x4*)((char*)cbL + (size_t)(r >> 4) * 1024 + c * 256 + (r & 15) * 16) = w;
        float ss = 0.f;
#pragma unroll
        for (int k = 0; k < 4; ++k) {
            ss = fmaf(a0[k], a0[k], ss); ss = fmaf(a1[k], a1[k], ss);
            ss = fmaf(b0[k], b0[k], ss); ss = fmaf(b1[k], b1[k], ss);
        }
        ss += __shfl_xor(ss, 1, 64);                  // sum the 4 chunks
        ss += __shfl_xor(ss, 2, 64);                  // (4 lanes share a row)
        if (c == 0) {
            int w8 = pk8<false>(-0.0625f * ss, 0.f, 0);
            ((unsigned char*)iniT)[(r & 15) * 32 + (r >> 4)] = (unsigned char)(w8 & 0xff);
        }
    }
    __syncthreads();

    const int wg = blockIdx.x * 16 + wid;        // 0..4095
    const int p0 = wg * 32;
    const int b  = p0 >> 12;                     // 32 | 4096 -> same b per wave
    const int s0 = (p0 & (HWs - 1)) + pl;
    const float* zbase = z + (size_t)b * (DC * HWs) + s0;

    // ---- z: 2 points (pl, pl+16) x 16 dims; fp32 kept + fp8 B-frags -------
    float zt[32];
#pragma unroll
    for (int j = 0; j < 8; ++j) {
        zt[j]      = zbase[(size_t)(8 * g + j) * HWs];
        zt[8 + j]  = zbase[(size_t)(32 + 8 * g + j) * HWs];
        zt[16 + j] = zbase[(size_t)(8 * g + j) * HWs + 16];
        zt[24 + j] = zbase[(size_t)(32 + 8 * g + j) * HWs + 16];
    }
    const long zA0 = mk64(pack4(SZ * zt[0],  SZ * zt[1],  SZ * zt[2],  SZ * zt[3]),
                          pack4(SZ * zt[4],  SZ * zt[5],  SZ * zt[6],  SZ * zt[7]));
    const long zA1 = mk64(pack4(SZ * zt[8],  SZ * zt[9],  SZ * zt[10], SZ * zt[11]),
                          pack4(SZ * zt[12], SZ * zt[13], SZ * zt[14], SZ * zt[15]));
    const long zB0 = mk64(pack4(SZ * zt[16], SZ * zt[17], SZ * zt[18], SZ * zt[19]),
                          pack4(SZ * zt[20], SZ * zt[21], SZ * zt[22], SZ * zt[23]));
    const long zB1 = mk64(pack4(SZ * zt[24], SZ * zt[25], SZ * zt[26], SZ * zt[27]),
                          pack4(SZ * zt[28], SZ * zt[29], SZ * zt[30], SZ * zt[31]));

    // per-lane ini bytes for codes 16t+pl, t=0..31
    const i32x4 iw0 = *(const i32x4*)((const char*)iniT + pl * 32);
    const i32x4 iw1 = *(const i32x4*)((const char*)iniT + pl * 32 + 16);
    const unsigned gmask = (g == 0) ? 0xffu : 0u;
    const long bunit = (g == 0) ? 0x38L : 0L;    // fp8 1.0 at k=0
    const f32x4 cb4 = {CBASE, CBASE, CBASE, CBASE};
    const char* cbbase = (const char*)cbL + lane * 16;   // linear in lane

    unsigned best0 = 0u, best1 = 0u;
#pragma unroll
    for (int t = 0; t < 32; ++t) {
        const unsigned wrd = (t < 16) ? (unsigned)iw0[(t >> 2) & 3]
                                      : (unsigned)iw1[((t - 16) >> 2) & 3];
        const long a_ini = (long)((wrd >> ((t & 3) * 8)) & gmask);
        i32x4 aw = *(const i32x4*)(cbbase + (size_t)t * 1024);   // conflict-free
        long A0 = mk64(aw[0], aw[1]);            // dims 8g..8g+7
        long A1 = mk64(aw[2], aw[3]);            // dims 32+8g..32+8g+7
        f32x4 ia = __builtin_amdgcn_mfma_f32_16x16x32_fp8_fp8(a_ini, bunit, cb4, 0, 0, 0);
        f32x4 acc0 = __builtin_amdgcn_mfma_f32_16x16x32_fp8_fp8(A0, zA0, ia, 0, 0, 0);
        acc0 = __builtin_amdgcn_mfma_f32_16x16x32_fp8_fp8(A1, zA1, acc0, 0, 0, 0);
        f32x4 acc1 = __builtin_amdgcn_mfma_f32_16x16x32_fp8_fp8(A0, zB0, ia, 0, 0, 0);
        acc1 = __builtin_amdgcn_mfma_f32_16x16x32_fp8_fp8(A1, zB1, acc1, 0, 0, 0);
#pragma unroll
        for (int j = 0; j < 4; ++j) {
            const unsigned code = (unsigned)(16 * t + 4 * g + j);
            unsigned u0 = __builtin_bit_cast(unsigned, acc0[j]) | code;
            unsigned u1 = __builtin_bit_cast(unsigned, acc1[j]) | code;
            best0 = best0 > u0 ? best0 : u0;
            best1 = best1 > u1 ? best1 : u1;
        }
    }

    // argmax across the 4 g-groups holding the same point
#pragma unroll
    for (int m = 16; m <= 32; m <<= 1) {
        unsigned o0 = (unsigned)__shfl_xor((int)best0, m, 64);
        unsigned o1 = (unsigned)__shfl_xor((int)best1, m, 64);
        best0 = best0 > o0 ? best0 : o0;
        best1 = best1 > o1 ? best1 : o1;
    }
    const int bidx0 = best0 & 511, bidx1 = best1 & 511;

    // epilogue: gather exact fp32 code rows (L2-hot), nt-store out, loss
    float err = 0.f;
    float* obase = outq + (size_t)b * (DC * HWs) + s0;
    {
        const float* qp = cbf + (size_t)bidx0 * DC + 8 * g;
        f32x4 q0 = *(const f32x4*)(qp);
        f32x4 q1 = *(const f32x4*)(qp + 4);
        f32x4 q2 = *(const f32x4*)(qp + 32);
        f32x4 q3 = *(const f32x4*)(qp + 36);
#pragma unroll
        for (int j = 0; j < 4; ++j) {
            size_t o0_ = (size_t)(8 * g + j) * HWs;
            size_t o1_ = (size_t)(8 * g + 4 + j) * HWs;
            size_t o2_ = (size_t)(32 + 8 * g + j) * HWs;
            size_t o3_ = (size_t)(32 + 8 * g + 4 + j) * HWs;
            __builtin_nontemporal_store(q0[j], &obase[o0_]);
            float d0 = q0[j] - zt[j];      err = fmaf(d0, d0, err);
            __builtin_nontemporal_store(q1[j], &obase[o1_]);
            float d1 = q1[j] - zt[4 + j];  err = fmaf(d1, d1, err);
            __builtin_nontemporal_store(q2[j], &obase[o2_]);
            float d2 = q2[j] - zt[8 + j];  err = fmaf(d2, d2, err);
            __builtin_nontemporal_store(q3[j], &obase[o3_]);
            float d3 = q3[j] - zt[12 + j]; err = fmaf(d3, d3, err);
        }
    }
    {
        const float* qp = cbf + (size_t)bidx1 * DC + 8 * g;
        f32x4 q0 = *(const f32x4*)(qp);
        f32x4 q1 = *(const f32x4*)(qp + 4);
        f32x4 q2 = *(const f32x4*)(qp + 32);
        f32x4 q3 = *(const f32x4*)(qp + 36);
#pragma unroll
        for (int j = 0; j < 4; ++j) {
            size_t o0_ = (size_t)(8 * g + j) * HWs + 16;
            size_t o1_ = (size_t)(8 * g + 4 + j) * HWs + 16;
            size_t o2_ = (size_t)(32 + 8 * g + j) * HWs + 16;
            size_t o3_ = (size_t)(32 + 8 * g + 4 + j) * HWs + 16;
            __builtin_nontemporal_store(q0[j], &obase[o0_]);
            float d0 = q0[j] - zt[16 + j]; err = fmaf(d0, d0, err);
            __builtin_nontemporal_store(q1[j], &obase[o1_]);
            float d1 = q1[j] - zt[20 + j]; err = fmaf(d1, d1, err);
            __builtin_nontemporal_store(q2[j], &obase[o2_]);
            float d2 = q2[j] - zt[24 + j]; err = fmaf(d2, d2, err);
            __builtin_nontemporal_store(q3[j], &obase[o3_]);
            float d3 = q3[j] - zt[28 + j]; err = fmaf(d3, d3, err);
        }
    }

    // wave reduce -> per-wave partial
#pragma unroll
    for (int off = 32; off; off >>= 1) err += __shfl_down(err, off, 64);
    if (lane == 0) partial[wg] = err;
}

// --- final loss reduction ---------------------------------------------------
__global__ __launch_bounds__(256) void vq_loss(const float* __restrict__ partial,
                                               float* __restrict__ loss_out) {
    float s = 0.f;
#pragma unroll
    for (int q = 0; q < NGRP / 256; ++q) s += partial[q * 256 + threadIdx.x];
#pragma unroll
    for (int off = 32; off; off >>= 1) s += __shfl_down(s, off, 64);
    __shared__ float red[4];
    if ((threadIdx.x & 63) == 0) red[threadIdx.x >> 6] = s;
    __syncthreads();
    if (threadIdx.x == 0)
        loss_out[0] = 1.25f * ((red[0] + red[1]) + (red[2] + red[3])) / 8388608.0f;
}

extern "C" void kernel_launch(void* const* d_in, const int* in_sizes, int n_in,
                              void* d_out, int out_size, void* d_ws, size_t ws_size,
                              hipStream_t stream) {
    const float* z   = (const float*)d_in[0];    // [32,64,64,64] f32
    const float* cbf = (const float*)d_in[1];    // [512,64] f32
    float* outq = (float*)d_out;                 // 8388608 + 1 (loss)
    float* loss = outq + 8388608;
    float* partial = (float*)d_ws;               // 4096 f32

    vq_search<<<NBLK, 1024, 0, stream>>>(z, cbf, outq, partial);
    vq_loss<<<1, 256, 0, stream>>>(partial, loss);
}

// Round 22
// 20.665 us; speedup vs baseline: 1.6498x; 1.0169x over previous
//
#include <hip/hip_runtime.h>

typedef float f32x4 __attribute__((ext_vector_type(4)));
typedef int   i32x4 __attribute__((ext_vector_type(4)));

#define KC 512
#define DC 64
#define HWs 4096
#define NPTS 131072
#define NGRP 4096              // 32 points per wave
#define NBLK 256               // 16 waves/block, 512 pts/block, 1 block/CU
#define SE 512.0f              // codebook scale (e' = 512 e)
#define SZ 64.0f               // z scale (z' = 64 z)
#define CBASE 4096.0f          // keeps packed scores positive

template <bool HI>
static __device__ inline int pk8(float a, float b, int old) {
    return __builtin_amdgcn_cvt_pk_fp8_f32(a, b, old, HI);
}
static __device__ inline long mk64(int lo, int hi) {
    return (long)(((unsigned long)(unsigned)hi << 32) | (unsigned)lo);
}
static __device__ inline int pack4(float a, float b, float c, float d) {
    int w = pk8<false>(a, b, 0);
    return pk8<true>(c, d, w);
}

// --- fused: staging + MFMA search (R21 champion + non-temporal z loads) -----
// One 1024-thread block per CU (staging paid once/CU).  Output stores AND z
// loads are stream-once -> nontemporal: the 67 MB of streaming traffic stays
// out of L2, preserving the L2-hot fp32 codebook rows (epilogue gather) and
// staging reads.  score = CBASE - 0.5*SZ*SE*||e||^2 + z'.e' (argmax == argmin
// distance); norm folded into ini-MFMA; LDS image entry j = t*64+g*16+pl at
// byte j*16 -> loop read lane*16+t*1024 linear in lane (conflict-free);
// zt kept in regs for the loss.
__global__ __launch_bounds__(1024, 4) void vq_search(const float* __restrict__ z,
                                                     const float* __restrict__ cbf,
                                                     float* __restrict__ outq,
                                                     float* __restrict__ partial) {
    __shared__ unsigned int cbL[KC * 16];   // 32 KB fp8 image (tile order)
    __shared__ unsigned int iniT[128];      // 512 ini bytes, [pl][t]
    const int tid = threadIdx.x;
    const int lane = tid & 63, wid = tid >> 6;   // 16 waves
    const int g = lane >> 4, pl = lane & 15;

    // ---- stage: fp32 codebook (coalesced) -> fp8 LDS image + ini bytes ----
    for (int pass = 0; pass < 2; ++pass) {
        const int i = pass * 1024 + tid;              // 4 consecutive thr = 1 row
        const int r = i >> 2, c = i & 3;
        const float* src = cbf + (size_t)r * DC + 8 * c;
        f32x4 a0 = *(const f32x4*)(src);
        f32x4 a1 = *(const f32x4*)(src + 4);
        f32x4 b0 = *(const f32x4*)(src + 32);
        f32x4 b1 = *(const f32x4*)(src + 36);
        a0 *= SE; a1 *= SE; b0 *= SE; b1 *= SE;
        i32x4 w = {pack4(a0[0], a0[1], a0[2], a0[3]),     // dims 8c..8c+3
                   pack4(a1[0], a1[1], a1[2], a1[3]),     // dims 8c+4..8c+7
                   pack4(b0[0], b0[1], b0[2], b0[3]),     // dims 32+8c..+3
                   pack4(b1[0], b1[1], b1[2], b1[3])};    // dims 32+8c+4..+7
        // entry j = (r>>4)*64 + c*16 + (r&15); byte j*16
        *(i32x4*)((char*)cbL + (size_t)(r >> 4) * 1024 + c * 256 + (r & 15) * 16) = w;
        float ss = 0.f;
#pragma unroll
        for (int k = 0; k < 4; ++k) {
            ss = fmaf(a0[k], a0[k], ss); ss = fmaf(a1[k], a1[k], ss);
            ss = fmaf(b0[k], b0[k], ss); ss = fmaf(b1[k], b1[k], ss);
        }
        ss += __shfl_xor(ss, 1, 64);                  // sum the 4 chunks
        ss += __shfl_xor(ss, 2, 64);                  // (4 lanes share a row)
        if (c == 0) {
            int w8 = pk8<false>(-0.0625f * ss, 0.f, 0);
            ((unsigned char*)iniT)[(r & 15) * 32 + (r >> 4)] = (unsigned char)(w8 & 0xff);
        }
    }
    __syncthreads();

    const int wg = blockIdx.x * 16 + wid;        // 0..4095
    const int p0 = wg * 32;
    const int b  = p0 >> 12;                     // 32 | 4096 -> same b per wave
    const int s0 = (p0 & (HWs - 1)) + pl;
    const float* zbase = z + (size_t)b * (DC * HWs) + s0;

    // ---- z: stream-once nontemporal loads; fp32 kept + fp8 B-frags --------
    float zt[32];
#pragma unroll
    for (int j = 0; j < 8; ++j) {
        zt[j]      = __builtin_nontemporal_load(&zbase[(size_t)(8 * g + j) * HWs]);
        zt[8 + j]  = __builtin_nontemporal_load(&zbase[(size_t)(32 + 8 * g + j) * HWs]);
        zt[16 + j] = __builtin_nontemporal_load(&zbase[(size_t)(8 * g + j) * HWs + 16]);
        zt[24 + j] = __builtin_nontemporal_load(&zbase[(size_t)(32 + 8 * g + j) * HWs + 16]);
    }
    const long zA0 = mk64(pack4(SZ * zt[0],  SZ * zt[1],  SZ * zt[2],  SZ * zt[3]),
                          pack4(SZ * zt[4],  SZ * zt[5],  SZ * zt[6],  SZ * zt[7]));
    const long zA1 = mk64(pack4(SZ * zt[8],  SZ * zt[9],  SZ * zt[10], SZ * zt[11]),
                          pack4(SZ * zt[12], SZ * zt[13], SZ * zt[14], SZ * zt[15]));
    const long zB0 = mk64(pack4(SZ * zt[16], SZ * zt[17], SZ * zt[18], SZ * zt[19]),
                          pack4(SZ * zt[20], SZ * zt[21], SZ * zt[22], SZ * zt[23]));
    const long zB1 = mk64(pack4(SZ * zt[24], SZ * zt[25], SZ * zt[26], SZ * zt[27]),
                          pack4(SZ * zt[28], SZ * zt[29], SZ * zt[30], SZ * zt[31]));

    // per-lane ini bytes for codes 16t+pl, t=0..31
    const i32x4 iw0 = *(const i32x4*)((const char*)iniT + pl * 32);
    const i32x4 iw1 = *(const i32x4*)((const char*)iniT + pl * 32 + 16);
    const unsigned gmask = (g == 0) ? 0xffu : 0u;
    const long bunit = (g == 0) ? 0x38L : 0L;    // fp8 1.0 at k=0
    const f32x4 cb4 = {CBASE, CBASE, CBASE, CBASE};
    const char* cbbase = (const char*)cbL + lane * 16;   // linear in lane

    unsigned best0 = 0u, best1 = 0u;
#pragma unroll
    for (int t = 0; t < 32; ++t) {
        const unsigned wrd = (t < 16) ? (unsigned)iw0[(t >> 2) & 3]
                                      : (unsigned)iw1[((t - 16) >> 2) & 3];
        const long a_ini = (long)((wrd >> ((t & 3) * 8)) & gmask);
        i32x4 aw = *(const i32x4*)(cbbase + (size_t)t * 1024);   // conflict-free
        long A0 = mk64(aw[0], aw[1]);            // dims 8g..8g+7
        long A1 = mk64(aw[2], aw[3]);            // dims 32+8g..32+8g+7
        f32x4 ia = __builtin_amdgcn_mfma_f32_16x16x32_fp8_fp8(a_ini, bunit, cb4, 0, 0, 0);
        f32x4 acc0 = __builtin_amdgcn_mfma_f32_16x16x32_fp8_fp8(A0, zA0, ia, 0, 0, 0);
        acc0 = __builtin_amdgcn_mfma_f32_16x16x32_fp8_fp8(A1, zA1, acc0, 0, 0, 0);
        f32x4 acc1 = __builtin_amdgcn_mfma_f32_16x16x32_fp8_fp8(A0, zB0, ia, 0, 0, 0);
        acc1 = __builtin_amdgcn_mfma_f32_16x16x32_fp8_fp8(A1, zB1, acc1, 0, 0, 0);
#pragma unroll
        for (int j = 0; j < 4; ++j) {
            const unsigned code = (unsigned)(16 * t + 4 * g + j);
            unsigned u0 = __builtin_bit_cast(unsigned, acc0[j]) | code;
            unsigned u1 = __builtin_bit_cast(unsigned, acc1[j]) | code;
            best0 = best0 > u0 ? best0 : u0;
            best1 = best1 > u1 ? best1 : u1;
        }
    }

    // argmax across the 4 g-groups holding the same point
#pragma unroll
    for (int m = 16; m <= 32; m <<= 1) {
        unsigned o0 = (unsigned)__shfl_xor((int)best0, m, 64);
        unsigned o1 = (unsigned)__shfl_xor((int)best1, m, 64);
        best0 = best0 > o0 ? best0 : o0;
        best1 = best1 > o1 ? best1 : o1;
    }
    const int bidx0 = best0 & 511, bidx1 = best1 & 511;

    // epilogue: gather exact fp32 code rows (L2-hot), nt-store out, loss
    float err = 0.f;
    float* obase = outq + (size_t)b * (DC * HWs) + s0;
    {
        const float* qp = cbf + (size_t)bidx0 * DC + 8 * g;
        f32x4 q0 = *(const f32x4*)(qp);
        f32x4 q1 = *(const f32x4*)(qp + 4);
        f32x4 q2 = *(const f32x4*)(qp + 32);
        f32x4 q3 = *(const f32x4*)(qp + 36);
#pragma unroll
        for (int j = 0; j < 4; ++j) {
            size_t o0_ = (size_t)(8 * g + j) * HWs;
            size_t o1_ = (size_t)(8 * g + 4 + j) * HWs;
            size_t o2_ = (size_t)(32 + 8 * g + j) * HWs;
            size_t o3_ = (size_t)(32 + 8 * g + 4 + j) * HWs;
            __builtin_nontemporal_store(q0[j], &obase[o0_]);
            float d0 = q0[j] - zt[j];      err = fmaf(d0, d0, err);
            __builtin_nontemporal_store(q1[j], &obase[o1_]);
            float d1 = q1[j] - zt[4 + j];  err = fmaf(d1, d1, err);
            __builtin_nontemporal_store(q2[j], &obase[o2_]);
            float d2 = q2[j] - zt[8 + j];  err = fmaf(d2, d2, err);
            __builtin_nontemporal_store(q3[j], &obase[o3_]);
            float d3 = q3[j] - zt[12 + j]; err = fmaf(d3, d3, err);
        }
    }
    {
        const float* qp = cbf + (size_t)bidx1 * DC + 8 * g;
        f32x4 q0 = *(const f32x4*)(qp);
        f32x4 q1 = *(const f32x4*)(qp + 4);
        f32x4 q2 = *(const f32x4*)(qp + 32);
        f32x4 q3 = *(const f32x4*)(qp + 36);
#pragma unroll
        for (int j = 0; j < 4; ++j) {
            size_t o0_ = (size_t)(8 * g + j) * HWs + 16;
            size_t o1_ = (size_t)(8 * g + 4 + j) * HWs + 16;
            size_t o2_ = (size_t)(32 + 8 * g + j) * HWs + 16;
            size_t o3_ = (size_t)(32 + 8 * g + 4 + j) * HWs + 16;
            __builtin_nontemporal_store(q0[j], &obase[o0_]);
            float d0 = q0[j] - zt[16 + j]; err = fmaf(d0, d0, err);
            __builtin_nontemporal_store(q1[j], &obase[o1_]);
            float d1 = q1[j] - zt[20 + j]; err = fmaf(d1, d1, err);
            __builtin_nontemporal_store(q2[j], &obase[o2_]);
            float d2 = q2[j] - zt[24 + j]; err = fmaf(d2, d2, err);
            __builtin_nontemporal_store(q3[j], &obase[o3_]);
            float d3 = q3[j] - zt[28 + j]; err = fmaf(d3, d3, err);
        }
    }

    // wave reduce -> per-wave partial
#pragma unroll
    for (int off = 32; off; off >>= 1) err += __shfl_down(err, off, 64);
    if (lane == 0) partial[wg] = err;
}

// --- final loss reduction ---------------------------------------------------
__global__ __launch_bounds__(256) void vq_loss(const float* __restrict__ partial,
                                               float* __restrict__ loss_out) {
    float s = 0.f;
#pragma unroll
    for (int q = 0; q < NGRP / 256; ++q) s += partial[q * 256 + threadIdx.x];
#pragma unroll
    for (int off = 32; off; off >>= 1) s += __shfl_down(s, off, 64);
    __shared__ float red[4];
    if ((threadIdx.x & 63) == 0) red[threadIdx.x >> 6] = s;
    __syncthreads();
    if (threadIdx.x == 0)
        loss_out[0] = 1.25f * ((red[0] + red[1]) + (red[2] + red[3])) / 8388608.0f;
}

extern "C" void kernel_launch(void* const* d_in, const int* in_sizes, int n_in,
                              void* d_out, int out_size, void* d_ws, size_t ws_size,
                              hipStream_t stream) {
    const float* z   = (const float*)d_in[0];    // [32,64,64,64] f32
    const float* cbf = (const float*)d_in[1];    // [512,64] f32
    float* outq = (float*)d_out;                 // 8388608 + 1 (loss)
    float* loss = outq + 8388608;
    float* partial = (float*)d_ws;               // 4096 f32

    vq_search<<<NBLK, 1024, 0, stream>>>(z, cbf, outq, partial);
    vq_loss<<<1, 256, 0, stream>>>(partial, loss);
}